// Round 6
// baseline (133.506 us; speedup 1.0000x reference)
//
#include <hip/hip_runtime.h>
#include <hip/hip_bf16.h>

typedef short short8 __attribute__((ext_vector_type(8)));
typedef float f32x4 __attribute__((ext_vector_type(4)));

#define HD 64
#define N_EN 8
#define N_AL 7
#define E_FEAT 9
#define A_FEAT 10
#define OWN_FEAT 16
#define N_ACT 14
#define EW2 641
#define AW2 640

// GEMM K sizes (padded to multiples of 32)
#define KE 640   // enemy: 576 P | 9 sef | 16 own | 1 const | 8 aid | 14 act | 16 pad
#define KA 672   // ally : 640 P | 10 sef | 22 pad
#define KG 160   // gru  : 64 x | 64 h | 1 const | 31 pad
#define KU 96    // u    : 64 hh | 1 const | 31 pad
#define KSE 20
#define KSA 21
#define KSG 5
#define KSU 3

// B-fragment tables in ws (ushort units)
#define BE_OFF 0
#define BE_CNT (KSE*4*64*8)
#define BA_OFF (BE_OFF+BE_CNT)
#define BA_CNT (KSA*4*64*8)
#define BG_OFF (BA_OFF+BA_CNT)
#define BG_CNT (KSG*16*64*8)
#define BU_OFF (BG_OFF+BG_CNT)
#define BU_CNT (KSU*5*64*8)
#define WS_SHORTS (BU_OFF+BU_CNT)   // 132608 shorts = 265216 B

// LDS layout (bytes). Regions reuse the P area across phases.
#define P_STRIDE 676          // ushorts/row (>= KA, mult of 4)
#define LDS_AG 0              // A_gru [16] rows, stride 328 B (164 us)
#define LDS_GATES 8192        // gates [16] rows, stride 520 B
#define LDS_AU 17024          // A_u [16] rows, stride 200 B
#define LDS_U 0               // u_lds [16][66] f32
#define LDS_BYTES 21632

__device__ __forceinline__ ushort f2u(float x) {
    __hip_bfloat16 b = __float2bfloat16(x);
    ushort u; __builtin_memcpy(&u, &b, 2); return u;
}
__device__ __forceinline__ float u2f(uint u) {
    union { uint x; float f; } c; c.x = u << 16; return c.f;
}
__device__ __forceinline__ uint pk2(float a, float b) {
    return (uint)f2u(a) | ((uint)f2u(b) << 16);
}
__device__ __forceinline__ float sigm(float x) { return 1.f / (1.f + __expf(-x)); }
__device__ __forceinline__ float wave_sum(float v) {
    #pragma unroll
    for (int o = 1; o < 64; o <<= 1) v += __shfl_xor(v, o);
    return v;
}
// A-fragment: two ds_read_b64 at k-slot base; elems 0-3 = kk, 4-7 = kk+16
__device__ __forceinline__ short8 lda(const char* base, int row, int strideB, int s, int g) {
    const char* p = base + row * strideB + s * 64 + g * 8;
    union { short8 v; uint2 q[2]; } u;
    u.q[0] = *(const uint2*)p;
    u.q[1] = *(const uint2*)(p + 32);
    return u.v;
}

// ---------------- prep: build B-fragment tables ----------------
__global__ __launch_bounds__(256) void prep_kernel(
    const float* __restrict__ he_w2, const float* __restrict__ he_b2,
    const float* __restrict__ ha_w2, const float* __restrict__ ha_b2,
    const float* __restrict__ fc1_own_w, const float* __restrict__ fc1_own_b,
    const float* __restrict__ agent_id_emb, const float* __restrict__ action_id_emb,
    const float* __restrict__ gru_w_ih, const float* __restrict__ gru_w_hh,
    const float* __restrict__ gru_b_ih, const float* __restrict__ gru_b_hh,
    const float* __restrict__ fc2_w, const float* __restrict__ fc2_b,
    ushort* __restrict__ ws)
{
    const int GE = KSE * 4, GA = KSA * 4, GG = KSG * 16, GU = KSU * 5;
    const int total = (GE + GA + GG + GU) * 64;
    int idx = blockIdx.x * 256 + threadIdx.x;
    if (idx >= total) return;
    int grp = idx >> 6, lane = idx & 63;
    int g = lane >> 4, col16 = lane & 15;
    int table, s, t, slot;
    if (grp < GE)           { table = 0; int q = grp;            s = q / 4;  t = q % 4;  slot = q * 64 + lane; }
    else if (grp < GE + GA) { table = 1; int q = grp - GE;       s = q / 4;  t = q % 4;  slot = q * 64 + lane; }
    else if (grp < GE + GA + GG) { table = 2; int q = grp - GE - GA; s = q / 16; t = q % 16; slot = q * 64 + lane; }
    else                    { table = 3; int q = grp - GE - GA - GG; s = q / 5; t = q % 5; slot = q * 64 + lane; }
    const int j = t * 16 + col16;
    ushort out[8];
    #pragma unroll
    for (int e = 0; e < 8; ++e) {
        int kk = 32 * s + 4 * g + (e & 3) + 16 * (e >> 2);
        float v = 0.f;
        if (table == 0) {
            if (kk < 576)      { int f = kk >> 6, k = kk & 63; v = he_w2[k * EW2 + f * HD + j]; }
            else if (kk < 585) { int f = kk - 576; v = he_b2[f * HD + j]; }
            else if (kk < 601) { int f = kk - 585; v = fc1_own_w[f * HD + j]; }
            else if (kk == 601){ v = fc1_own_b[j]; }
            else if (kk < 610) { int a = kk - 602; v = agent_id_emb[a * HD + j]; }
            else if (kk < 624) { int a = kk - 610; v = action_id_emb[a * HD + j]; }
        } else if (table == 1) {
            if (kk < 640)      { int f = kk >> 6, k = kk & 63; v = ha_w2[k * AW2 + f * HD + j]; }
            else if (kk < 650) { int f = kk - 640; v = ha_b2[f * HD + j]; }
        } else if (table == 2) {
            int gb = j >> 6, c = j & 63;
            if (gb <= 1) {                 // merged r / z gates
                int jj = gb * 64 + c;
                if (kk < 64)        v = gru_w_ih[jj * HD + kk];
                else if (kk < 128)  v = gru_w_hh[jj * HD + kk - 64];
                else if (kk == 128) v = gru_b_ih[jj] + gru_b_hh[jj];
            } else if (gb == 2) {          // i_n
                int jj = 128 + c;
                if (kk < 64)        v = gru_w_ih[jj * HD + kk];
                else if (kk == 128) v = gru_b_ih[jj];
            } else {                       // h_n
                int jj = 128 + c;
                if (kk >= 64 && kk < 128) v = gru_w_hh[jj * HD + kk - 64];
                else if (kk == 128)       v = gru_b_hh[jj];
            }
        } else {
            if (j < 64) {
                if (kk < 64)       v = he_w2[j * EW2 + 576 + kk];
                else if (kk == 64) v = he_w2[j * EW2 + 640];
            } else if (j < 70) {
                int o = j - 64;
                if (kk < 64)       v = fc2_w[kk * 6 + o];
                else if (kk == 64) v = fc2_b[o];
            } else if (j == 70) {
                if (kk < 64)       v = he_b2[576 + kk];
                else if (kk == 64) v = he_b2[640];
            }
        }
        out[e] = f2u(v);
    }
    ushort* dst = ws + ((table == 0) ? BE_OFF : (table == 1) ? BA_OFF : (table == 2) ? BG_OFF : BU_OFF);
    *(short8*)(dst + slot * 8) = *(short8*)out;
}

// ---------------- main ----------------
__global__ __launch_bounds__(256, 2) void agent_kernel(
    const float* __restrict__ own_feats,
    const float* __restrict__ enemy_feats,
    const float* __restrict__ ally_feats,
    const float* __restrict__ hidden_state,
    const int*  __restrict__ agent_idx,
    const int*  __restrict__ last_act_idx,
    const float* __restrict__ he_w1, const float* __restrict__ he_b1,
    const float* __restrict__ ha_w1, const float* __restrict__ ha_b1,
    const ushort* __restrict__ ws,
    float* __restrict__ out_q, float* __restrict__ out_hh)
{
    __shared__ __align__(16) char smem[LDS_BYTES];
    const int tid  = threadIdx.x;
    const int lane = tid & 63;
    const int wv   = tid >> 6;
    const int n0   = blockIdx.x * 16;
    const int arow = lane & 15;     // A row / B col / D col
    const int g    = lane >> 4;     // k-slot group; D rows 4g..4g+3
    ushort* P = (ushort*)smem;

    // ===== Phase 1: enemy P-build (wave-private rows 4wv..4wv+3) =====
    {
        float w1[E_FEAT];
        #pragma unroll
        for (int f = 0; f < E_FEAT; ++f) w1[f] = he_w1[f * HD + lane];
        const float b1 = he_b1[lane];
        #pragma unroll
        for (int rr = 0; rr < 4; ++rr) {
            const int row = wv * 4 + rr, n = n0 + row;
            const float* efb = enemy_feats + (size_t)n * (N_EN * E_FEAT);
            float pf[E_FEAT], sf[E_FEAT];
            #pragma unroll
            for (int f = 0; f < E_FEAT; ++f) { pf[f] = 0.f; sf[f] = 0.f; }
            #pragma unroll
            for (int e = 0; e < N_EN; ++e) {
                float ef[E_FEAT];
                #pragma unroll
                for (int f = 0; f < E_FEAT; ++f) ef[f] = efb[e * E_FEAT + f];
                float acc = b1;
                #pragma unroll
                for (int f = 0; f < E_FEAT; ++f) acc += ef[f] * w1[f];
                const float r = fmaxf(acc, 0.f);
                #pragma unroll
                for (int f = 0; f < E_FEAT; ++f) { pf[f] += r * ef[f]; sf[f] += ef[f]; }
            }
            ushort* Pr = P + row * P_STRIDE;
            #pragma unroll
            for (int f = 0; f < E_FEAT; ++f) Pr[f * HD + lane] = f2u(pf[f]);
            if (lane == 0) {
                #pragma unroll
                for (int f = 0; f < E_FEAT; ++f) Pr[576 + f] = f2u(sf[f]);
                Pr[601] = 0x3F80;
            }
            if (lane < OWN_FEAT) Pr[585 + lane] = f2u(own_feats[(size_t)n * OWN_FEAT + lane]);
            const int ai = agent_idx[n], la = last_act_idx[n];
            if (lane < 8)      Pr[602 + lane] = (lane == ai) ? 0x3F80 : 0;
            if (lane < N_ACT)  Pr[610 + lane] = (lane == la) ? 0x3F80 : 0;
            if (lane < 16)     Pr[624 + lane] = 0;
        }
    }
    __syncthreads();

    // ===== Phase 2: enemy GEMM (acc shared with ally) =====
    f32x4 accE = {0.f, 0.f, 0.f, 0.f};
    for (int s = 0; s < KSE; ++s) {
        short8 a = lda(smem, arow, P_STRIDE * 2, s, g);
        short8 b = *(const short8*)(ws + BE_OFF + ((size_t)(s * 4 + wv) * 64 + lane) * 8);
        accE = __builtin_amdgcn_mfma_f32_16x16x32_bf16(a, b, accE, 0, 0, 0);
    }
    __syncthreads();

    // ===== Phase 3: ally P-build =====
    {
        float w1[A_FEAT];
        #pragma unroll
        for (int f = 0; f < A_FEAT; ++f) w1[f] = ha_w1[f * HD + lane];
        const float b1 = ha_b1[lane];
        #pragma unroll
        for (int rr = 0; rr < 4; ++rr) {
            const int row = wv * 4 + rr, n = n0 + row;
            const float* afb = ally_feats + (size_t)n * (N_AL * A_FEAT);
            float pf[A_FEAT], sf[A_FEAT];
            #pragma unroll
            for (int f = 0; f < A_FEAT; ++f) { pf[f] = 0.f; sf[f] = 0.f; }
            #pragma unroll
            for (int e = 0; e < N_AL; ++e) {
                float af[A_FEAT];
                #pragma unroll
                for (int f = 0; f < A_FEAT; ++f) af[f] = afb[e * A_FEAT + f];
                float acc = b1;
                #pragma unroll
                for (int f = 0; f < A_FEAT; ++f) acc += af[f] * w1[f];
                const float r = fmaxf(acc, 0.f);
                #pragma unroll
                for (int f = 0; f < A_FEAT; ++f) { pf[f] += r * af[f]; sf[f] += af[f]; }
            }
            ushort* Pr = P + row * P_STRIDE;
            #pragma unroll
            for (int f = 0; f < A_FEAT; ++f) Pr[f * HD + lane] = f2u(pf[f]);
            if (lane == 0) {
                #pragma unroll
                for (int f = 0; f < A_FEAT; ++f) Pr[640 + f] = f2u(sf[f]);
            }
            if (lane < 22) Pr[650 + lane] = 0;
        }
    }
    __syncthreads();

    // ===== Phase 4: ally GEMM (accumulate into accE) =====
    for (int s = 0; s < KSA; ++s) {
        short8 a = lda(smem, arow, P_STRIDE * 2, s, g);
        short8 b = *(const short8*)(ws + BA_OFF + ((size_t)(s * 4 + wv) * 64 + lane) * 8);
        accE = __builtin_amdgcn_mfma_f32_16x16x32_bf16(a, b, accE, 0, 0, 0);
    }
    __syncthreads();

    // ===== Phase 5: stage A_gru = [x | h | 1 | 0] =====
    #pragma unroll
    for (int j = 0; j < 4; ++j) {
        const int m = g * 4 + j;
        const float x = fmaxf(accE[j], 0.f);
        *(ushort*)(smem + LDS_AG + m * 328 + (wv * 16 + arow) * 2) = f2u(x);
    }
    {
        const int row = tid >> 4, c4 = (tid & 15) * 4;
        float4 h4 = *(const float4*)(hidden_state + (size_t)(n0 + row) * HD + c4);
        char* p = smem + LDS_AG + row * 328 + (64 + c4) * 2;
        *(uint*)p       = pk2(h4.x, h4.y);
        *(uint*)(p + 4) = pk2(h4.z, h4.w);
        if (tid < 16) *(ushort*)(smem + LDS_AG + tid * 328 + 128 * 2) = 0x3F80;
        for (int i = tid; i < 16 * 31; i += 256) {
            int r2 = i / 31, c = 129 + i % 31;
            *(ushort*)(smem + LDS_AG + r2 * 328 + c * 2) = 0;
        }
    }
    __syncthreads();

    // ===== Phase 6: GRU GEMM (N=256: r|z|i_n|h_n), wave wv owns j in [64wv,64wv+64) =====
    {
        f32x4 accG[4] = {{0.f,0.f,0.f,0.f},{0.f,0.f,0.f,0.f},{0.f,0.f,0.f,0.f},{0.f,0.f,0.f,0.f}};
        for (int s = 0; s < KSG; ++s) {
            short8 a = lda(smem + LDS_AG, arow, 328, s, g);
            #pragma unroll
            for (int tt = 0; tt < 4; ++tt) {
                const int t = wv * 4 + tt;
                short8 b = *(const short8*)(ws + BG_OFF + ((size_t)(s * 16 + t) * 64 + lane) * 8);
                accG[tt] = __builtin_amdgcn_mfma_f32_16x16x32_bf16(a, b, accG[tt], 0, 0, 0);
            }
        }
        #pragma unroll
        for (int tt = 0; tt < 4; ++tt)
            #pragma unroll
            for (int j = 0; j < 4; ++j) {
                const int m = g * 4 + j, jc = (wv * 4 + tt) * 16 + arow;
                *(ushort*)(smem + LDS_GATES + m * 520 + jc * 2) = f2u(accG[tt][j]);
            }
    }
    __syncthreads();

    // ===== Phase 7: pointwise GRU + stage A_u =====
    {
        const int row = tid >> 4, c4 = (tid & 15) * 4;
        const char* gb = smem + LDS_GATES + row * 520;
        uint2 rv = *(const uint2*)(gb + c4 * 2);
        uint2 zv = *(const uint2*)(gb + 128 + c4 * 2);
        uint2 iv = *(const uint2*)(gb + 256 + c4 * 2);
        uint2 nv = *(const uint2*)(gb + 384 + c4 * 2);
        float4 h4 = *(const float4*)(hidden_state + (size_t)(n0 + row) * HD + c4);
        float hr[4] = {u2f(rv.x & 0xffffu), u2f(rv.x >> 16), u2f(rv.y & 0xffffu), u2f(rv.y >> 16)};
        float hz[4] = {u2f(zv.x & 0xffffu), u2f(zv.x >> 16), u2f(zv.y & 0xffffu), u2f(zv.y >> 16)};
        float hi[4] = {u2f(iv.x & 0xffffu), u2f(iv.x >> 16), u2f(iv.y & 0xffffu), u2f(iv.y >> 16)};
        float hn[4] = {u2f(nv.x & 0xffffu), u2f(nv.x >> 16), u2f(nv.y & 0xffffu), u2f(nv.y >> 16)};
        float hcur[4] = {h4.x, h4.y, h4.z, h4.w};
        float hh[4];
        #pragma unroll
        for (int cc = 0; cc < 4; ++cc) {
            const float r = sigm(hr[cc]);
            const float z = sigm(hz[cc]);
            const float nng = tanhf(hi[cc] + r * hn[cc]);
            hh[cc] = (1.f - z) * nng + z * hcur[cc];
        }
        float4 o4 = make_float4(hh[0], hh[1], hh[2], hh[3]);
        *(float4*)(out_hh + (size_t)(n0 + row) * HD + c4) = o4;
        char* p = smem + LDS_AU + row * 200 + c4 * 2;
        *(uint*)p       = pk2(hh[0], hh[1]);
        *(uint*)(p + 4) = pk2(hh[2], hh[3]);
        if (tid < 16) *(ushort*)(smem + LDS_AU + tid * 200 + 64 * 2) = 0x3F80;
        for (int i = tid; i < 16 * 31; i += 256) {
            int r2 = i / 31, c = 65 + i % 31;
            *(ushort*)(smem + LDS_AU + r2 * 200 + c * 2) = 0;
        }
    }
    __syncthreads();

    // ===== Phase 8: u-GEMM (N=80: u[64] | fc2 q[6] | c | pad) =====
    {
        f32x4 accU = {0.f, 0.f, 0.f, 0.f};
        f32x4 accQ = {0.f, 0.f, 0.f, 0.f};
        for (int s = 0; s < KSU; ++s) {
            short8 a = lda(smem + LDS_AU, arow, 200, s, g);
            short8 b = *(const short8*)(ws + BU_OFF + ((size_t)(s * 5 + wv) * 64 + lane) * 8);
            accU = __builtin_amdgcn_mfma_f32_16x16x32_bf16(a, b, accU, 0, 0, 0);
            if (wv == 0) {
                short8 b2 = *(const short8*)(ws + BU_OFF + ((size_t)(s * 5 + 4) * 64 + lane) * 8);
                accQ = __builtin_amdgcn_mfma_f32_16x16x32_bf16(a, b2, accQ, 0, 0, 0);
            }
        }
        float* uld = (float*)(smem + LDS_U);
        #pragma unroll
        for (int j = 0; j < 4; ++j) {
            const int m = g * 4 + j;
            uld[m * 66 + wv * 16 + arow] = accU[j];
        }
        if (wv == 0) {
            #pragma unroll
            for (int j = 0; j < 4; ++j) {
                const int m = g * 4 + j;
                if (arow < 6)       out_q[(size_t)(n0 + m) * N_ACT + arow] = accQ[j];
                else if (arow == 6) uld[m * 66 + 64] = accQ[j];
            }
        }
    }
    __syncthreads();

    // ===== Phase 9: attack head =====
    {
        float w1[E_FEAT];
        #pragma unroll
        for (int f = 0; f < E_FEAT; ++f) w1[f] = he_w1[f * HD + lane];
        const float b1 = he_b1[lane];
        const float* uld = (const float*)(smem + LDS_U);
        #pragma unroll
        for (int rr = 0; rr < 4; ++rr) {
            const int row = wv * 4 + rr, n = n0 + row;
            const float uk = uld[row * 66 + lane];
            const float ct = uld[row * 66 + 64];
            const float* efb = enemy_feats + (size_t)n * (N_EN * E_FEAT);
            #pragma unroll
            for (int e = 0; e < N_EN; ++e) {
                float acc = b1;
                #pragma unroll
                for (int f = 0; f < E_FEAT; ++f) acc += efb[e * E_FEAT + f] * w1[f];
                float p = fmaxf(acc, 0.f) * uk;
                p = wave_sum(p);
                if (lane == e) out_q[(size_t)n * N_ACT + 6 + e] = p + ct;
            }
        }
    }
}

extern "C" void kernel_launch(void* const* d_in, const int* in_sizes, int n_in,
                              void* d_out, int out_size, void* d_ws, size_t ws_size,
                              hipStream_t stream) {
    const float* own_feats    = (const float*)d_in[0];
    const float* enemy_feats  = (const float*)d_in[1];
    const float* ally_feats   = (const float*)d_in[2];
    const float* hidden_state = (const float*)d_in[3];
    const int*  agent_idx     = (const int*)d_in[4];
    const int*  last_act      = (const int*)d_in[5];
    const float* fc1_own_w = (const float*)d_in[7];
    const float* fc1_own_b = (const float*)d_in[8];
    const float* agent_id_emb  = (const float*)d_in[9];
    const float* action_id_emb = (const float*)d_in[10];
    const float* he_w1 = (const float*)d_in[11];
    const float* he_b1 = (const float*)d_in[12];
    const float* he_w2 = (const float*)d_in[13];
    const float* he_b2 = (const float*)d_in[14];
    const float* ha_w1 = (const float*)d_in[15];
    const float* ha_b1 = (const float*)d_in[16];
    const float* ha_w2 = (const float*)d_in[17];
    const float* ha_b2 = (const float*)d_in[18];
    const float* gru_w_ih = (const float*)d_in[19];
    const float* gru_w_hh = (const float*)d_in[20];
    const float* gru_b_ih = (const float*)d_in[21];
    const float* gru_b_hh = (const float*)d_in[22];
    const float* fc2_w = (const float*)d_in[23];
    const float* fc2_b = (const float*)d_in[24];

    const int R = in_sizes[0] / OWN_FEAT;  // 32768
    ushort* ws = (ushort*)d_ws;
    float* out_q  = (float*)d_out;
    float* out_hh = out_q + (size_t)R * N_ACT;

    prep_kernel<<<65, 256, 0, stream>>>(
        he_w2, he_b2, ha_w2, ha_b2, fc1_own_w, fc1_own_b,
        agent_id_emb, action_id_emb, gru_w_ih, gru_w_hh, gru_b_ih, gru_b_hh,
        fc2_w, fc2_b, ws);

    agent_kernel<<<R / 16, 256, 0, stream>>>(
        own_feats, enemy_feats, ally_feats, hidden_state, agent_idx, last_act,
        he_w1, he_b1, ha_w1, ha_b1, ws, out_q, out_hh);
}